// Round 1
// baseline (320.536 us; speedup 1.0000x reference)
//
#include <hip/hip_runtime.h>

#define NB 8
#define NN 1024
#define NH 8
#define HD 96
#define DIM 768

typedef __bf16 bf16x8 __attribute__((ext_vector_type(8)));
typedef float f32x4 __attribute__((ext_vector_type(4)));

__device__ __forceinline__ ushort f2bf(float f) {
  uint u = __float_as_uint(f);
  u += 0x7fffu + ((u >> 16) & 1u);
  return (ushort)(u >> 16);
}

// ---------------- K0b: proj_w [768][768] f32 -> wT bf16 [j][d] ----------------
__global__ __launch_bounds__(256) void k_prep_w(const float* __restrict__ pw,
                                                ushort* __restrict__ wT) {
  __shared__ ushort tile[64][72];
  int d0 = blockIdx.x * 64;
  int j0 = blockIdx.y * 64;
  int t = threadIdx.x;
  {
    int r = t >> 2;          // d within tile
    int ch = (t & 3) * 16;   // j chunk
    const float* src = pw + (size_t)(d0 + r) * DIM + j0 + ch;
#pragma unroll
    for (int i = 0; i < 16; i += 4) {
      float4 v = *(const float4*)(src + i);
      tile[ch + i + 0][r] = f2bf(v.x);
      tile[ch + i + 1][r] = f2bf(v.y);
      tile[ch + i + 2][r] = f2bf(v.z);
      tile[ch + i + 3][r] = f2bf(v.w);
    }
  }
  __syncthreads();
  {
    int j = t >> 2;
    int ch = (t & 3) * 16;   // d chunk
    union { ushort u[16]; uint4 v[2]; } tmp;
#pragma unroll
    for (int i = 0; i < 16; ++i) tmp.u[i] = tile[j][ch + i];
    uint4* dst = (uint4*)(wT + (size_t)(j0 + j) * DIM + d0 + ch);
    dst[0] = tmp.v[0]; dst[1] = tmp.v[1];
  }
}

// ---------------- K1: 3x3 SAME conv per 16x16x3 token image -> q bf16 ----------------
__global__ __launch_bounds__(256) void k_conv(const float* __restrict__ x,
                                              const float* __restrict__ w,
                                              ushort* __restrict__ q) {
  __shared__ float xs[768];
  __shared__ float ws[81];
  __shared__ ushort os[768];
  int token = blockIdx.x;
  int t = threadIdx.x;
  const float4* xin = (const float4*)(x + (size_t)token * DIM);
  if (t < 192) ((float4*)xs)[t] = xin[t];
  if (t < 81) ws[t] = w[t];
  __syncthreads();
  int r = t >> 4, c = t & 15;
  float a0 = 0.f, a1 = 0.f, a2 = 0.f;
#pragma unroll
  for (int dr = 0; dr < 3; ++dr) {
    int rr = r + dr - 1;
    bool rok = (rr >= 0) & (rr < 16);
#pragma unroll
    for (int dc = 0; dc < 3; ++dc) {
      int cc = c + dc - 1;
      bool ok = rok & (cc >= 0) & (cc < 16);
#pragma unroll
      for (int ci = 0; ci < 3; ++ci) {
        int idx = ok ? (rr * 16 + cc) * 3 + ci : 0;
        float xv = xs[idx];
        xv = ok ? xv : 0.f;
        const float* wp = ws + ((dr * 3 + dc) * 3 + ci) * 3;
        a0 += xv * wp[0]; a1 += xv * wp[1]; a2 += xv * wp[2];
      }
    }
  }
  os[t * 3 + 0] = f2bf(a0);
  os[t * 3 + 1] = f2bf(a1);
  os[t * 3 + 2] = f2bf(a2);
  __syncthreads();
  uint4* dst = (uint4*)(q + (size_t)token * DIM);
  if (t < 96) dst[t] = ((const uint4*)os)[t];
}

// ---------------- K1b: q [b][n][d] -> qT [b][d][n] (bf16) ----------------
__global__ __launch_bounds__(256) void k_transpose_q(const ushort* __restrict__ q,
                                                     ushort* __restrict__ qT) {
  __shared__ ushort tile[64][72];
  int bb = blockIdx.z;
  int n0 = blockIdx.x * 64;
  int d0 = blockIdx.y * 64;
  int t = threadIdx.x;
  {
    int r = t >> 2;          // n within tile
    int cq = (t & 3) * 16;   // d chunk
    const ushort* src = q + ((size_t)(bb * NN) + n0 + r) * DIM + d0 + cq;
    uint4 v0 = *(const uint4*)src;
    uint4 v1 = *(const uint4*)(src + 8);
    *(uint4*)&tile[r][cq] = v0;
    *(uint4*)&tile[r][cq + 8] = v1;
  }
  __syncthreads();
  {
    int d = t >> 2;
    int nch = (t & 3) * 16;
    union { ushort u[16]; uint4 v[2]; } tmp;
#pragma unroll
    for (int j = 0; j < 16; ++j) tmp.u[j] = tile[nch + j][d];
    uint4* dst = (uint4*)(qT + ((size_t)(bb * DIM) + d0 + d) * NN + n0 + nch);
    dst[0] = tmp.v[0]; dst[1] = tmp.v[1];
  }
}

// ---------------- K2: S = scale * q_h q_h^T, logits fp32 into attn region ----------------
__global__ __launch_bounds__(256) void k_qk(const ushort* __restrict__ q,
                                            float* __restrict__ attn) {
  __shared__ ushort As[128][104];
  __shared__ ushort Bs[128][104];
  int bh = blockIdx.z;
  int bb = bh >> 3;
  int h = bh & 7;
  int m0 = blockIdx.x * 128;
  int n0 = blockIdx.y * 128;
  int t = threadIdx.x;
  const ushort* qb = q + (size_t)bb * NN * DIM + h * HD;
  for (int i = t; i < 1536; i += 256) {
    int row = i / 12;
    int ck = (i % 12) * 8;
    *(uint4*)&As[row][ck] = *(const uint4*)(qb + (size_t)(m0 + row) * DIM + ck);
    *(uint4*)&Bs[row][ck] = *(const uint4*)(qb + (size_t)(n0 + row) * DIM + ck);
  }
  __syncthreads();
  int wv = t >> 6, lane = t & 63;
  int wr = (wv >> 1) * 64, wc = (wv & 1) * 64;
  int lm = lane & 15, lg = lane >> 4;
  f32x4 acc[4][4] = {};
#pragma unroll
  for (int ks = 0; ks < 3; ++ks) {
    bf16x8 af[4], bfr[4];
#pragma unroll
    for (int mi = 0; mi < 4; ++mi)
      af[mi] = *(const bf16x8*)&As[wr + mi * 16 + lm][ks * 32 + lg * 8];
#pragma unroll
    for (int ni = 0; ni < 4; ++ni)
      bfr[ni] = *(const bf16x8*)&Bs[wc + ni * 16 + lm][ks * 32 + lg * 8];
#pragma unroll
    for (int mi = 0; mi < 4; ++mi)
#pragma unroll
      for (int ni = 0; ni < 4; ++ni)
        acc[mi][ni] = __builtin_amdgcn_mfma_f32_16x16x32_bf16(af[mi], bfr[ni], acc[mi][ni], 0, 0, 0);
  }
  const float scale = 0.10206207261596575f;  // 96^-0.5
  float* out = attn + (size_t)bh * NN * NN;
#pragma unroll
  for (int mi = 0; mi < 4; ++mi)
#pragma unroll
    for (int ni = 0; ni < 4; ++ni)
#pragma unroll
      for (int r = 0; r < 4; ++r) {
        int row = m0 + wr + mi * 16 + lg * 4 + r;
        int col = n0 + wc + ni * 16 + lm;
        out[(size_t)row * NN + col] = acc[mi][ni][r] * scale;
      }
}

// ---------------- K3: per (b,n): softmax over m for all 8 heads + head-mix + BN, in place ----------------
__global__ __launch_bounds__(256) void k_softmax_mix(float* __restrict__ attn,
    const float* __restrict__ rw, const float* __restrict__ rb,
    const float* __restrict__ gamma, const float* __restrict__ beta,
    const float* __restrict__ mean, const float* __restrict__ var) {
  __shared__ float sm[8][1024];
  __shared__ float wls[64];
  __shared__ float effs[8], effb[8], invsum[8];
  int bb = blockIdx.x >> 10;
  int n = blockIdx.x & 1023;
  int t = threadIdx.x;
  if (t < 64) wls[t] = rw[t];
  if (t >= 64 && t < 72) {
    int g = t - 64;
    float sc = gamma[g] / sqrtf(var[g] + 1e-3f);
    effs[g] = sc;
    effb[g] = (rb[g] - mean[g]) * sc + beta[g];
  }
#pragma unroll
  for (int h = 0; h < 8; ++h) {
    const float4* src = (const float4*)(attn + (((size_t)(bb * 8 + h) * NN) + n) * NN);
    ((float4*)sm[h])[t] = src[t];
  }
  __syncthreads();
  int wv = t >> 6, lane = t & 63;
#pragma unroll
  for (int hh = 0; hh < 2; ++hh) {
    int h = wv * 2 + hh;
    float v[16];
    float mx = -1e30f;
#pragma unroll
    for (int j = 0; j < 16; ++j) { v[j] = sm[h][lane + j * 64]; mx = fmaxf(mx, v[j]); }
#pragma unroll
    for (int o = 32; o; o >>= 1) mx = fmaxf(mx, __shfl_xor(mx, o));
    float s = 0.f;
#pragma unroll
    for (int j = 0; j < 16; ++j) { float e = __expf(v[j] - mx); s += e; sm[h][lane + j * 64] = e; }
#pragma unroll
    for (int o = 32; o; o >>= 1) s += __shfl_xor(s, o);
    if (lane == 0) invsum[h] = 1.f / s;
  }
  __syncthreads();
  float4 av[8];
#pragma unroll
  for (int h = 0; h < 8; ++h) {
    av[h] = *((const float4*)&sm[h][t * 4]);
    float is = invsum[h];
    av[h].x *= is; av[h].y *= is; av[h].z *= is; av[h].w *= is;
  }
#pragma unroll
  for (int g = 0; g < 8; ++g) {
    float sc = effs[g], sh = effb[g];
    float4 res; res.x = 0.f; res.y = 0.f; res.z = 0.f; res.w = 0.f;
#pragma unroll
    for (int h = 0; h < 8; ++h) {
      float wv_ = wls[h * 8 + g];
      res.x += av[h].x * wv_; res.y += av[h].y * wv_;
      res.z += av[h].z * wv_; res.w += av[h].w * wv_;
    }
    res.x = res.x * sc + sh; res.y = res.y * sc + sh;
    res.z = res.z * sc + sh; res.w = res.w * sc + sh;
    *(float4*)(attn + (((size_t)(bb * 8 + g) * NN) + n) * NN + t * 4) = res;
  }
}

// ---------------- K5: out[n][g*96+d] = sum_m attn_next[b,g,n,m] q[b,m,g*96+d] (bf16 MFMA) ----------------
__global__ __launch_bounds__(256) void k_pv(const float* __restrict__ attn,
                                            const ushort* __restrict__ qT,
                                            ushort* __restrict__ outb) {
  __shared__ ushort As[128][72];
  __shared__ ushort Bs[96][72];
  int bg = blockIdx.y;
  int bb = bg >> 3, g = bg & 7;
  int n0 = blockIdx.x * 128;
  int t = threadIdx.x;
  const float* abase = attn + ((size_t)bg * NN + n0) * NN;
  const ushort* vbase = qT + ((size_t)bb * DIM + g * HD) * NN;
  int wv = t >> 6, lane = t & 63;
  int lm = lane & 15, lg = lane >> 4;
  f32x4 acc[2][6] = {};
  for (int kk = 0; kk < 16; ++kk) {
    int k0 = kk * 64;
    __syncthreads();
    for (int i = t; i < 2048; i += 256) {
      int row = i >> 4;
      int c = (i & 15) * 4;
      float4 vv = *(const float4*)(abase + (size_t)row * NN + k0 + c);
      ushort4 u;
      u.x = f2bf(vv.x); u.y = f2bf(vv.y); u.z = f2bf(vv.z); u.w = f2bf(vv.w);
      *(ushort4*)&As[row][c] = u;
    }
    for (int i = t; i < 768; i += 256) {
      int d = i >> 3;
      int c = (i & 7) * 8;
      *(uint4*)&Bs[d][c] = *(const uint4*)(vbase + (size_t)d * NN + k0 + c);
    }
    __syncthreads();
#pragma unroll
    for (int ks = 0; ks < 2; ++ks) {
      bf16x8 af[2], bfr[6];
#pragma unroll
      for (int mi = 0; mi < 2; ++mi)
        af[mi] = *(const bf16x8*)&As[wv * 32 + mi * 16 + lm][ks * 32 + lg * 8];
#pragma unroll
      for (int ni = 0; ni < 6; ++ni)
        bfr[ni] = *(const bf16x8*)&Bs[ni * 16 + lm][ks * 32 + lg * 8];
#pragma unroll
      for (int mi = 0; mi < 2; ++mi)
#pragma unroll
        for (int ni = 0; ni < 6; ++ni)
          acc[mi][ni] = __builtin_amdgcn_mfma_f32_16x16x32_bf16(af[mi], bfr[ni], acc[mi][ni], 0, 0, 0);
    }
  }
#pragma unroll
  for (int mi = 0; mi < 2; ++mi)
#pragma unroll
    for (int ni = 0; ni < 6; ++ni)
#pragma unroll
      for (int r = 0; r < 4; ++r) {
        int row = n0 + wv * 32 + mi * 16 + lg * 4 + r;
        int col = g * HD + ni * 16 + lm;
        outb[(size_t)(bb * NN + row) * DIM + col] = f2bf(acc[mi][ni][r]);
      }
}

// ---------------- K6: xo = out @ proj_w + proj_b (bf16 MFMA, fp32 out) ----------------
__global__ __launch_bounds__(256) void k_proj(const ushort* __restrict__ outb,
                                              const ushort* __restrict__ wT,
                                              const float* __restrict__ pb,
                                              float* __restrict__ xo) {
  __shared__ ushort As[128][72];
  __shared__ ushort Bs[128][72];
  int m0 = blockIdx.x * 128;
  int j0 = blockIdx.y * 128;
  int t = threadIdx.x;
  int wv = t >> 6, lane = t & 63;
  int wr = (wv >> 1) * 64, wc = (wv & 1) * 64;
  int lm = lane & 15, lg = lane >> 4;
  f32x4 acc[4][4] = {};
  for (int kk = 0; kk < 12; ++kk) {
    int k0 = kk * 64;
    __syncthreads();
    for (int i = t; i < 1024; i += 256) {
      int row = i >> 3;
      int c = (i & 7) * 8;
      *(uint4*)&As[row][c] = *(const uint4*)(outb + (size_t)(m0 + row) * DIM + k0 + c);
      *(uint4*)&Bs[row][c] = *(const uint4*)(wT + (size_t)(j0 + row) * DIM + k0 + c);
    }
    __syncthreads();
#pragma unroll
    for (int ks = 0; ks < 2; ++ks) {
      bf16x8 af[4], bfr[4];
#pragma unroll
      for (int mi = 0; mi < 4; ++mi)
        af[mi] = *(const bf16x8*)&As[wr + mi * 16 + lm][ks * 32 + lg * 8];
#pragma unroll
      for (int ni = 0; ni < 4; ++ni)
        bfr[ni] = *(const bf16x8*)&Bs[wc + ni * 16 + lm][ks * 32 + lg * 8];
#pragma unroll
      for (int mi = 0; mi < 4; ++mi)
#pragma unroll
        for (int ni = 0; ni < 4; ++ni)
          acc[mi][ni] = __builtin_amdgcn_mfma_f32_16x16x32_bf16(af[mi], bfr[ni], acc[mi][ni], 0, 0, 0);
    }
  }
#pragma unroll
  for (int ni = 0; ni < 4; ++ni) {
    int col = j0 + wc + ni * 16 + lm;
    float bias = pb[col];
#pragma unroll
    for (int mi = 0; mi < 4; ++mi)
#pragma unroll
      for (int r = 0; r < 4; ++r) {
        int row = m0 + wr + mi * 16 + lg * 4 + r;
        xo[(size_t)row * DIM + col] = acc[mi][ni][r] + bias;
      }
  }
}

extern "C" void kernel_launch(void* const* d_in, const int* in_sizes, int n_in,
                              void* d_out, int out_size, void* d_ws, size_t ws_size,
                              hipStream_t stream) {
  (void)in_sizes; (void)n_in; (void)out_size; (void)ws_size;
  const float* x       = (const float*)d_in[0];
  const float* qconv_w = (const float*)d_in[1];
  const float* rw      = (const float*)d_in[2];
  const float* rb      = (const float*)d_in[3];
  const float* gamma   = (const float*)d_in[4];
  const float* beta    = (const float*)d_in[5];
  const float* mean    = (const float*)d_in[6];
  const float* var     = (const float*)d_in[7];
  const float* pw      = (const float*)d_in[8];
  const float* pb      = (const float*)d_in[9];

  float* xo   = (float*)d_out;
  float* attn = xo + (size_t)NB * NN * DIM;  // attn_next region, also used for logits

  char* ws = (char*)d_ws;
  ushort* q    = (ushort*)(ws);                 // [8][1024][768] bf16: 12,582,912 B
  ushort* qT   = (ushort*)(ws + 12582912);      // [8][768][1024] bf16: 12,582,912 B
  ushort* wT   = (ushort*)(ws + 25165824);      // [768][768] bf16:      1,179,648 B
  ushort* outb = (ushort*)(ws + 26345472);      // [8192][768] bf16:    12,582,912 B

  hipLaunchKernelGGL(k_prep_w, dim3(12, 12), dim3(256), 0, stream, pw, wT);
  hipLaunchKernelGGL(k_conv, dim3(NB * NN), dim3(256), 0, stream, x, qconv_w, q);
  hipLaunchKernelGGL(k_transpose_q, dim3(16, 12, NB), dim3(256), 0, stream, q, qT);
  hipLaunchKernelGGL(k_qk, dim3(8, 8, NB * NH), dim3(256), 0, stream, q, attn);
  hipLaunchKernelGGL(k_softmax_mix, dim3(NB * NN), dim3(256), 0, stream, attn,
                     rw, rb, gamma, beta, mean, var);
  hipLaunchKernelGGL(k_pv, dim3(8, NB * NH), dim3(256), 0, stream, attn, qT, outb);
  hipLaunchKernelGGL(k_proj, dim3(64, 6), dim3(256), 0, stream, outb, wT, pb, xo);
}

// Round 3
// 290.560 us; speedup vs baseline: 1.1032x; 1.1032x over previous
//
#include <hip/hip_runtime.h>

#define NB 8
#define NN 1024
#define NH 8
#define HD 96
#define DIM 768

typedef __bf16 bf16x8 __attribute__((ext_vector_type(8)));
typedef float f32x4 __attribute__((ext_vector_type(4)));
typedef unsigned short u16x8 __attribute__((ext_vector_type(8)));

__device__ __forceinline__ ushort f2bf(float f) {
  uint u = __float_as_uint(f);
  u += 0x7fffu + ((u >> 16) & 1u);
  return (ushort)(u >> 16);
}
__device__ __forceinline__ float bf2f(ushort u) {
  return __uint_as_float(((uint)u) << 16);
}

// ---------------- K0b: proj_w [768][768] f32 -> wT bf16 [j][d] ----------------
__global__ __launch_bounds__(256) void k_prep_w(const float* __restrict__ pw,
                                                ushort* __restrict__ wT) {
  __shared__ ushort tile[64][72];
  int d0 = blockIdx.x * 64;
  int j0 = blockIdx.y * 64;
  int t = threadIdx.x;
  {
    int r = t >> 2;
    int ch = (t & 3) * 16;
    const float* src = pw + (size_t)(d0 + r) * DIM + j0 + ch;
#pragma unroll
    for (int i = 0; i < 16; i += 4) {
      float4 v = *(const float4*)(src + i);
      tile[ch + i + 0][r] = f2bf(v.x);
      tile[ch + i + 1][r] = f2bf(v.y);
      tile[ch + i + 2][r] = f2bf(v.z);
      tile[ch + i + 3][r] = f2bf(v.w);
    }
  }
  __syncthreads();
  {
    int j = t >> 2;
    int ch = (t & 3) * 16;
    union { ushort u[16]; uint4 v[2]; } tmp;
#pragma unroll
    for (int i = 0; i < 16; ++i) tmp.u[i] = tile[j][ch + i];
    uint4* dst = (uint4*)(wT + (size_t)(j0 + j) * DIM + d0 + ch);
    dst[0] = tmp.v[0]; dst[1] = tmp.v[1];
  }
}

// ---------------- K1: 3x3 SAME conv per 16x16x3 token image -> q bf16 ----------------
__global__ __launch_bounds__(256) void k_conv(const float* __restrict__ x,
                                              const float* __restrict__ w,
                                              ushort* __restrict__ q) {
  __shared__ float xs[768];
  __shared__ float ws[81];
  __shared__ ushort os[768];
  int token = blockIdx.x;
  int t = threadIdx.x;
  const float4* xin = (const float4*)(x + (size_t)token * DIM);
  if (t < 192) ((float4*)xs)[t] = xin[t];
  if (t < 81) ws[t] = w[t];
  __syncthreads();
  int r = t >> 4, c = t & 15;
  float a0 = 0.f, a1 = 0.f, a2 = 0.f;
#pragma unroll
  for (int dr = 0; dr < 3; ++dr) {
    int rr = r + dr - 1;
    bool rok = (rr >= 0) & (rr < 16);
#pragma unroll
    for (int dc = 0; dc < 3; ++dc) {
      int cc = c + dc - 1;
      bool ok = rok & (cc >= 0) & (cc < 16);
#pragma unroll
      for (int ci = 0; ci < 3; ++ci) {
        int idx = ok ? (rr * 16 + cc) * 3 + ci : 0;
        float xv = xs[idx];
        xv = ok ? xv : 0.f;
        const float* wp = ws + ((dr * 3 + dc) * 3 + ci) * 3;
        a0 += xv * wp[0]; a1 += xv * wp[1]; a2 += xv * wp[2];
      }
    }
  }
  os[t * 3 + 0] = f2bf(a0);
  os[t * 3 + 1] = f2bf(a1);
  os[t * 3 + 2] = f2bf(a2);
  __syncthreads();
  uint4* dst = (uint4*)(q + (size_t)token * DIM);
  if (t < 96) dst[t] = ((const uint4*)os)[t];
}

// ---------------- K1b: q [b][n][d] -> qT [b][d][n] (bf16) ----------------
__global__ __launch_bounds__(256) void k_transpose_q(const ushort* __restrict__ q,
                                                     ushort* __restrict__ qT) {
  __shared__ ushort tile[64][72];
  int bb = blockIdx.z;
  int n0 = blockIdx.x * 64;
  int d0 = blockIdx.y * 64;
  int t = threadIdx.x;
  {
    int r = t >> 2;
    int cq = (t & 3) * 16;
    const ushort* src = q + ((size_t)(bb * NN) + n0 + r) * DIM + d0 + cq;
    uint4 v0 = *(const uint4*)src;
    uint4 v1 = *(const uint4*)(src + 8);
    *(uint4*)&tile[r][cq] = v0;
    *(uint4*)&tile[r][cq + 8] = v1;
  }
  __syncthreads();
  {
    int d = t >> 2;
    int nch = (t & 3) * 16;
    union { ushort u[16]; uint4 v[2]; } tmp;
#pragma unroll
    for (int j = 0; j < 16; ++j) tmp.u[j] = tile[nch + j][d];
    uint4* dst = (uint4*)(qT + ((size_t)(bb * DIM) + d0 + d) * NN + n0 + nch);
    dst[0] = tmp.v[0]; dst[1] = tmp.v[1];
  }
}

// ---------------- K1c: colsum[b][d] = sum_n q[b][n][d] ----------------
__global__ __launch_bounds__(128) void k_colsum(const ushort* __restrict__ q,
                                                float* __restrict__ cs) {
  int bb = blockIdx.y;
  int c = blockIdx.x * 128 + threadIdx.x;
  const ushort* p = q + (size_t)bb * NN * DIM + c;
  float s = 0.f;
#pragma unroll 16
  for (int n = 0; n < NN; ++n) s += bf2f(p[(size_t)n * DIM]);
  cs[bb * DIM + c] = s;
}

// ---------------- K2: fused QK^T + softmax + head-mix/BN + attn write + PV ----------------
// 512 threads = 8 waves. Wave w: head h=w for QK^T/softmax, channel g=w for mix/PV.
// Block: (b, 32-row n-tile). lin&7 -> batch (XCD locality: each XCD reads one batch's q/qT).
__global__ __launch_bounds__(512, 2) void k_attn_fused(
    const ushort* __restrict__ q, const ushort* __restrict__ qT,
    const float* __restrict__ cs,
    const float* __restrict__ rw, const float* __restrict__ rb,
    const float* __restrict__ gamma, const float* __restrict__ beta,
    const float* __restrict__ mean, const float* __restrict__ var,
    float* __restrict__ attn, ushort* __restrict__ outb) {
  __shared__ ushort P[16384];  // [8][32][64] bf16, XOR-swizzled rows, 32 KB

  const int lin = blockIdx.x;
  const int bb = lin & 7;
  const int nt = lin >> 3;
  const int n0 = nt * 32;
  const int t = threadIdx.x;
  const int w = t >> 6, lane = t & 63;
  const int lm = lane & 15, lg = lane >> 4;
  const float scale = 0.10206207261596575f;  // 96^-0.5

  // mix weights for this wave's g = w; BN affine constants
  float wreg[8];
#pragma unroll
  for (int h = 0; h < 8; ++h) wreg[h] = rw[h * 8 + w];
  const float effs = gamma[w] * __frsqrt_rn(var[w] + 1e-3f);
  const float effb = (rb[w] - mean[w]) * effs + beta[w];

  const ushort* qb = q + (size_t)bb * NN * DIM;
  const ushort* vb = qT + (size_t)bb * DIM * NN;

  // Q fragments for head w: [nf][ks]
  bf16x8 qf[2][3];
#pragma unroll
  for (int nf = 0; nf < 2; ++nf)
#pragma unroll
    for (int ks = 0; ks < 3; ++ks)
      qf[nf][ks] = *(const bf16x8*)(qb + (size_t)(n0 + nf * 16 + lm) * DIM
                                     + w * HD + ks * 32 + lg * 8);

  // ---------------- pass A: rowsums of exp(S*scale) ----------------
  float rs[2][4];
#pragma unroll
  for (int nf = 0; nf < 2; ++nf)
#pragma unroll
    for (int r = 0; r < 4; ++r) rs[nf][r] = 0.f;

  for (int mt = 0; mt < 16; ++mt) {
    const int m0 = mt * 64;
    f32x4 sacc[2][4] = {};
#pragma unroll
    for (int ks = 0; ks < 3; ++ks) {
      bf16x8 kf[4];
#pragma unroll
      for (int mf = 0; mf < 4; ++mf)
        kf[mf] = *(const bf16x8*)(qb + (size_t)(m0 + mf * 16 + lm) * DIM
                                   + w * HD + ks * 32 + lg * 8);
#pragma unroll
      for (int nf = 0; nf < 2; ++nf)
#pragma unroll
        for (int mf = 0; mf < 4; ++mf)
          sacc[nf][mf] = __builtin_amdgcn_mfma_f32_16x16x32_bf16(qf[nf][ks], kf[mf], sacc[nf][mf], 0, 0, 0);
    }
#pragma unroll
    for (int nf = 0; nf < 2; ++nf)
#pragma unroll
      for (int mf = 0; mf < 4; ++mf)
#pragma unroll
        for (int r = 0; r < 4; ++r)
          rs[nf][r] += __expf(sacc[nf][mf][r] * scale);
  }
  // reduce over the 16 col-lanes (butterfly, broadcast to all)
  float inv[2][4];
#pragma unroll
  for (int nf = 0; nf < 2; ++nf)
#pragma unroll
    for (int r = 0; r < 4; ++r) {
      float s = rs[nf][r];
      s += __shfl_xor(s, 1); s += __shfl_xor(s, 2);
      s += __shfl_xor(s, 4); s += __shfl_xor(s, 8);
      inv[nf][r] = 1.f / s;
    }

  // ---------------- pass B ----------------
  f32x4 oacc[2][6] = {};  // [nf][df] PV accumulator (raw mix, affine at epilogue)

  for (int mt = 0; mt < 16; ++mt) {
    const int m0 = mt * 64;
    // phase 1: recompute S (bitwise-identical MFMA order), normalize, p -> LDS
    {
      f32x4 sacc[2][4] = {};
#pragma unroll
      for (int ks = 0; ks < 3; ++ks) {
        bf16x8 kf[4];
#pragma unroll
        for (int mf = 0; mf < 4; ++mf)
          kf[mf] = *(const bf16x8*)(qb + (size_t)(m0 + mf * 16 + lm) * DIM
                                     + w * HD + ks * 32 + lg * 8);
#pragma unroll
        for (int nf = 0; nf < 2; ++nf)
#pragma unroll
          for (int mf = 0; mf < 4; ++mf)
            sacc[nf][mf] = __builtin_amdgcn_mfma_f32_16x16x32_bf16(qf[nf][ks], kf[mf], sacc[nf][mf], 0, 0, 0);
      }
#pragma unroll
      for (int nf = 0; nf < 2; ++nf)
#pragma unroll
        for (int mf = 0; mf < 4; ++mf)
#pragma unroll
          for (int r = 0; r < 4; ++r) {
            float e = __expf(sacc[nf][mf][r] * scale) * inv[nf][r];
            int n = nf * 16 + lg * 4 + r;
            int mbyte = 2 * (mf * 16 + lm);
            int addr = w * 4096 + n * 128 + (mbyte ^ ((n & 7) << 4));
            *(ushort*)((char*)P + addr) = f2bf(e);
          }
    }
    // prefetch V fragments (independent of LDS) to overlap with mix phase
    bf16x8 vf[2][6];
#pragma unroll
    for (int ks = 0; ks < 2; ++ks)
#pragma unroll
      for (int df = 0; df < 6; ++df)
        vf[ks][df] = *(const bf16x8*)(vb + (size_t)(w * HD + df * 16 + lm) * NN
                                       + m0 + ks * 32 + lg * 8);
    __syncthreads();
    // phase 2: mix heads -> g=w, BN-affine store to attn, pack pm frags
    bf16x8 pmf[2][2];  // [nf][ks]
#pragma unroll
    for (int nf = 0; nf < 2; ++nf) {
      int n = nf * 16 + lm;
      int swz = (n & 7) << 4;
#pragma unroll
      for (int ks = 0; ks < 2; ++ks) {
        int rbase = n * 128 + ((2 * (ks * 32 + lg * 8)) ^ swz);
        float mix[8];
#pragma unroll
        for (int j = 0; j < 8; ++j) mix[j] = 0.f;
#pragma unroll
        for (int h = 0; h < 8; ++h) {
          u16x8 pu = *(const u16x8*)((char*)P + h * 4096 + rbase);
#pragma unroll
          for (int j = 0; j < 8; ++j) mix[j] += bf2f(pu[j]) * wreg[h];
        }
        f32x4 o0, o1;
        o0[0] = mix[0] * effs + effb; o0[1] = mix[1] * effs + effb;
        o0[2] = mix[2] * effs + effb; o0[3] = mix[3] * effs + effb;
        o1[0] = mix[4] * effs + effb; o1[1] = mix[5] * effs + effb;
        o1[2] = mix[6] * effs + effb; o1[3] = mix[7] * effs + effb;
        size_t arow = ((size_t)(bb * 8 + w) * NN + (n0 + n)) * NN + m0 + ks * 32 + lg * 8;
        __builtin_nontemporal_store(o0, (f32x4*)(attn + arow));
        __builtin_nontemporal_store(o1, (f32x4*)(attn + arow + 4));
        u16x8 pk;
#pragma unroll
        for (int j = 0; j < 8; ++j) pk[j] = f2bf(mix[j]);
        pmf[nf][ks] = *(bf16x8*)&pk;
      }
    }
    __syncthreads();
    // phase 3: PV MFMA
#pragma unroll
    for (int ks = 0; ks < 2; ++ks)
#pragma unroll
      for (int df = 0; df < 6; ++df)
#pragma unroll
        for (int nf = 0; nf < 2; ++nf)
          oacc[nf][df] = __builtin_amdgcn_mfma_f32_16x16x32_bf16(pmf[nf][ks], vf[ks][df], oacc[nf][df], 0, 0, 0);
  }

  // epilogue: outb = bf16(effs*acc + effb*colsum)
#pragma unroll
  for (int df = 0; df < 6; ++df) {
    int col = w * HD + df * 16 + lm;
    float csv = cs[bb * DIM + col] * effb;
#pragma unroll
    for (int nf = 0; nf < 2; ++nf)
#pragma unroll
      for (int r = 0; r < 4; ++r) {
        int row = n0 + nf * 16 + lg * 4 + r;
        outb[(size_t)(bb * NN + row) * DIM + col] =
            f2bf(oacc[nf][df][r] * effs + csv);
      }
  }
}

// ---------------- K6: xo = out @ proj_w + proj_b (bf16 MFMA, fp32 out) ----------------
__global__ __launch_bounds__(256) void k_proj(const ushort* __restrict__ outb,
                                              const ushort* __restrict__ wT,
                                              const float* __restrict__ pb,
                                              float* __restrict__ xo) {
  __shared__ ushort As[128][72];
  __shared__ ushort Bs[128][72];
  int m0 = blockIdx.x * 128;
  int j0 = blockIdx.y * 128;
  int t = threadIdx.x;
  int wv = t >> 6, lane = t & 63;
  int wr = (wv >> 1) * 64, wc = (wv & 1) * 64;
  int lm = lane & 15, lg = lane >> 4;
  f32x4 acc[4][4] = {};
  for (int kk = 0; kk < 12; ++kk) {
    int k0 = kk * 64;
    __syncthreads();
    for (int i = t; i < 1024; i += 256) {
      int row = i >> 3;
      int c = (i & 7) * 8;
      *(uint4*)&As[row][c] = *(const uint4*)(outb + (size_t)(m0 + row) * DIM + k0 + c);
      *(uint4*)&Bs[row][c] = *(const uint4*)(wT + (size_t)(j0 + row) * DIM + k0 + c);
    }
    __syncthreads();
#pragma unroll
    for (int ks = 0; ks < 2; ++ks) {
      bf16x8 af[4], bfr[4];
#pragma unroll
      for (int mi = 0; mi < 4; ++mi)
        af[mi] = *(const bf16x8*)&As[wr + mi * 16 + lm][ks * 32 + lg * 8];
#pragma unroll
      for (int ni = 0; ni < 4; ++ni)
        bfr[ni] = *(const bf16x8*)&Bs[wc + ni * 16 + lm][ks * 32 + lg * 8];
#pragma unroll
      for (int mi = 0; mi < 4; ++mi)
#pragma unroll
        for (int ni = 0; ni < 4; ++ni)
          acc[mi][ni] = __builtin_amdgcn_mfma_f32_16x16x32_bf16(af[mi], bfr[ni], acc[mi][ni], 0, 0, 0);
    }
  }
#pragma unroll
  for (int ni = 0; ni < 4; ++ni) {
    int col = j0 + wc + ni * 16 + lm;
    float bias = pb[col];
#pragma unroll
    for (int mi = 0; mi < 4; ++mi)
#pragma unroll
      for (int r = 0; r < 4; ++r) {
        int row = m0 + wr + mi * 16 + lg * 4 + r;
        xo[(size_t)row * DIM + col] = acc[mi][ni][r] + bias;
      }
  }
}

extern "C" void kernel_launch(void* const* d_in, const int* in_sizes, int n_in,
                              void* d_out, int out_size, void* d_ws, size_t ws_size,
                              hipStream_t stream) {
  (void)in_sizes; (void)n_in; (void)out_size; (void)ws_size;
  const float* x       = (const float*)d_in[0];
  const float* qconv_w = (const float*)d_in[1];
  const float* rw      = (const float*)d_in[2];
  const float* rb      = (const float*)d_in[3];
  const float* gamma   = (const float*)d_in[4];
  const float* beta    = (const float*)d_in[5];
  const float* mean    = (const float*)d_in[6];
  const float* var     = (const float*)d_in[7];
  const float* pw      = (const float*)d_in[8];
  const float* pb      = (const float*)d_in[9];

  float* xo   = (float*)d_out;
  float* attn = xo + (size_t)NB * NN * DIM;  // attn_next output region

  char* ws = (char*)d_ws;
  ushort* q    = (ushort*)(ws);                 // [8][1024][768] bf16: 12,582,912 B
  ushort* qT   = (ushort*)(ws + 12582912);      // [8][768][1024] bf16: 12,582,912 B
  ushort* wT   = (ushort*)(ws + 25165824);      // [768][768] bf16:      1,179,648 B
  ushort* outb = (ushort*)(ws + 26345472);      // [8192][768] bf16:    12,582,912 B
  float*  csum = (float*)(ws + 38928384);       // [8][768] f32:            24,576 B

  hipLaunchKernelGGL(k_prep_w, dim3(12, 12), dim3(256), 0, stream, pw, wT);
  hipLaunchKernelGGL(k_conv, dim3(NB * NN), dim3(256), 0, stream, x, qconv_w, q);
  hipLaunchKernelGGL(k_transpose_q, dim3(16, 12, NB), dim3(256), 0, stream, q, qT);
  hipLaunchKernelGGL(k_colsum, dim3(6, NB), dim3(128), 0, stream, q, csum);
  hipLaunchKernelGGL(k_attn_fused, dim3(256), dim3(512), 0, stream, q, qT, csum,
                     rw, rb, gamma, beta, mean, var, attn, outb);
  hipLaunchKernelGGL(k_proj, dim3(64, 6), dim3(256), 0, stream, outb, wT, pb, xo);
}